// Round 1
// baseline (43.530 us; speedup 1.0000x reference)
//
#include <hip/hip_runtime.h>

#define NTHREADS 256
#define MAXN 8192

__global__ __launch_bounds__(NTHREADS, 2)
void dmrl_kernel(const float* __restrict__ preds,
                 const float* __restrict__ targets,
                 float* __restrict__ out,
                 double* __restrict__ acc,
                 unsigned int* __restrict__ cnt,
                 int N, double inv_pairs)
{
    __shared__ float2 tp[MAXN];   // 64 KiB exactly; reused as double scratch too

    const int tid  = threadIdx.x;
    const int lane = tid & 63;
    const int wave = tid >> 6;

    // ---- phase 1: margin = 0.25 * std(targets, ddof=1), per-block redundant ----
    double s = 0.0, s2 = 0.0;
    for (int j = tid; j < N; j += NTHREADS) {
        float t = targets[j];
        s  += (double)t;
        s2 += (double)t * (double)t;
    }
    #pragma unroll
    for (int off = 32; off > 0; off >>= 1) {
        s  += __shfl_down(s,  off, 64);
        s2 += __shfl_down(s2, off, 64);
    }
    double* red = (double*)tp;            // LDS scratch (before staging)
    if (lane == 0) { red[wave] = s; red[NTHREADS/64 + wave] = s2; }
    __syncthreads();
    if (tid == 0) {
        double S = 0.0, S2 = 0.0;
        for (int w = 0; w < NTHREADS/64; ++w) { S += red[w]; S2 += red[NTHREADS/64 + w]; }
        double mean = S / (double)N;
        double var  = (S2 - (double)N * mean * mean) / (double)(N - 1);
        ((float*)tp)[0] = (float)(0.25 * sqrt(var > 0.0 ? var : 0.0));
    }
    __syncthreads();
    const float margin = ((float*)tp)[0];
    __syncthreads();                      // everyone has margin before overwrite

    // ---- phase 2: stage (t, p) into LDS ----
    for (int j = tid; j < N; j += NTHREADS) {
        tp[j] = make_float2(targets[j], preds[j]);
    }
    __syncthreads();

    // ---- phase 3: all pairs i < j ----
    double total = 0.0;
    const int half = N >> 1;
    for (int r = blockIdx.x; r < half; r += gridDim.x) {
        #pragma unroll
        for (int side = 0; side < 2; ++side) {
            const int i = side ? (N - 1 - r) : r;
            const float2 ti = tp[i];
            float rowacc = 0.0f;
            for (int j = i + 1 + tid; j < N; j += NTHREADS) {
                float2 tj = tp[j];
                float tdiff = ti.x - tj.x;
                float pdiff = ti.y - tj.y;
                float sgn = (tdiff > 0.0f) ? 1.0f : ((tdiff < 0.0f) ? -1.0f : 0.0f);
                rowacc += fmaxf(fmaf(-sgn, pdiff, margin), 0.0f);
            }
            total += (double)rowacc;
        }
    }
    if ((N & 1) && blockIdx.x == 0) {     // middle row when N odd
        const int i = half;
        const float2 ti = tp[i];
        float rowacc = 0.0f;
        for (int j = i + 1 + tid; j < N; j += NTHREADS) {
            float2 tj = tp[j];
            float tdiff = ti.x - tj.x;
            float pdiff = ti.y - tj.y;
            float sgn = (tdiff > 0.0f) ? 1.0f : ((tdiff < 0.0f) ? -1.0f : 0.0f);
            rowacc += fmaxf(fmaf(-sgn, pdiff, margin), 0.0f);
        }
        total += (double)rowacc;
    }

    // ---- phase 4: block reduce + grid combine ----
    __syncthreads();                      // done reading tp; reuse as scratch
    #pragma unroll
    for (int off = 32; off > 0; off >>= 1) total += __shfl_down(total, off, 64);
    if (lane == 0) red[wave] = total;
    __syncthreads();
    if (tid == 0) {
        double bt = 0.0;
        for (int w = 0; w < NTHREADS/64; ++w) bt += red[w];
        atomicAdd(acc, bt);
        __threadfence();
        unsigned prev = atomicAdd(cnt, 1u);
        if (prev == gridDim.x - 1) {
            double tot = atomicAdd(acc, 0.0);   // atomic read of final value
            out[0] = (float)(tot * inv_pairs);
        }
    }
}

extern "C" void kernel_launch(void* const* d_in, const int* in_sizes, int n_in,
                              void* d_out, int out_size, void* d_ws, size_t ws_size,
                              hipStream_t stream) {
    const float* preds   = (const float*)d_in[0];
    const float* targets = (const float*)d_in[1];
    float* out = (float*)d_out;
    int N = in_sizes[0];

    double* acc = (double*)d_ws;
    unsigned int* cnt = (unsigned int*)((char*)d_ws + sizeof(double));
    hipMemsetAsync(d_ws, 0, sizeof(double) + sizeof(unsigned int), stream);

    double inv_pairs = 2.0 / ((double)N * (double)(N - 1));
    int half = N >> 1;
    int grid = half < 512 ? (half > 0 ? half : 1) : 512;

    dmrl_kernel<<<grid, NTHREADS, 0, stream>>>(preds, targets, out, acc, cnt, N, inv_pairs);
}